// Round 3
// baseline (167.062 us; speedup 1.0000x reference)
//
#include <hip/hip_runtime.h>

// ISTA T=5, LAM=0.1, B=L=4096, K=128.
// R6: barrier-free interior. u = corr(y - corr(y,h), rev(h)) == (interior)
//  one 255-tap correlation with G[t] = [t in [-63,64]] h[64-t] - ac[|t-1|].
//  Interior blocks read B-fragments (8 consecutive fp32 of one row) STRAIGHT
//  from global (L2-resident working set, 50 KB/block) -> no LDS staging, no
//  __syncthreads, pure per-wave streams with sliding 9-window registers.
//  r-truncation affects cols [0,64) u [L-64,L): exact two-pass edge blocks
//  (same launch, disjoint columns) fix those strips via LDS.
//  ISTA closed form (constant u): x_5 = 5*soft(s*u, LAM).

typedef __bf16 bf16;
typedef __bf16 bf16x4 __attribute__((ext_vector_type(4)));
typedef __bf16 bf16x8 __attribute__((ext_vector_type(8)));
typedef float f32x4 __attribute__((ext_vector_type(4)));

#define LC 512      // L-chunk per interior block
#define LAM 0.1f
// ws layout in bf16 elems (16-B aligned fragments):
#define WS_AG 0      // AG frag:  lane*128 + dd*8, dd<9
#define WS_A1 8192   // A1e frag: lane*64  + dd*8, dd<5
#define WS_A2 12288  // A2e frag: lane*64  + dd*8, dd<5
// edge-path LDS partition:
#define PYE 360      // y strip pitch (352 needed)
#define PRE 216      // r strip pitch (208 needed)

// ---------------- prep: G + lane-layout A-fragment tables ----------------
__global__ __launch_bounds__(256) void ista_prep(const float* __restrict__ h,
                                                 bf16* __restrict__ ws) {
  __shared__ float hs[256];    // h zero-padded
  __shared__ float acp[256];   // autocorr partials
  __shared__ bf16 gp[384];     // G[t] at p=t+144, zero outside
  const int tid = threadIdx.x;
  hs[tid] = (tid < 128) ? h[tid] : 0.f;
  gp[tid] = (bf16)0.f;
  if (tid < 128) gp[256 + tid] = (bf16)0.f;
  __syncthreads();
  const int tau = tid & 127;
  {  // split ac over two halves x 4 accumulators (short dep chains)
    const int m0 = (tid >> 7) * 64;
    float p0 = 0.f, p1 = 0.f, p2 = 0.f, p3 = 0.f;
    for (int m = m0; m < m0 + 64; m += 4) {
      p0 += hs[m] * hs[m + tau];     p1 += hs[m + 1] * hs[m + 1 + tau];
      p2 += hs[m + 2] * hs[m + 2 + tau]; p3 += hs[m + 3] * hs[m + 3 + tau];
    }
    acp[tid] = (p0 + p1) + (p2 + p3);
  }
  __syncthreads();
  if (tid < 128) {
    float ac = acp[tid] + acp[tid + 128];
    float g1 = (tau <= 63) ? hs[63 - tau] : 0.f;
    gp[145 + tau] = (bf16)(g1 - ac);
    if (tau > 0) {
      float g2 = (tau <= 64) ? hs[63 + tau] : 0.f;
      gp[145 - tau] = (bf16)(g2 - ac);
    }
  }
  __syncthreads();
  // AG lane-layout: A[m=li][k=quad*8+j] = G[144 + quad*8 - li + (dd-4)*32 + j]
  for (int i = tid; i < 1024; i += 256) {
    const int l = i >> 4, dd = i & 15;
    if (dd < 9) {
      const int o = 144 + (l >> 4) * 8 - (l & 15) + (dd - 4) * 32;
      bf16x8 a;
#pragma unroll
      for (int j = 0; j < 8; ++j) a[j] = gp[o + j];
      *reinterpret_cast<bf16x8*>(ws + WS_AG + l * 128 + dd * 8) = a;
    }
  }
  // edge Toeplitz tables: h1p[p]=h[p-64], h2p[p]=-h[191-p] (zero outside)
  for (int i = tid; i < 512; i += 256) {
    const int l = i >> 3, dd = i & 7;
    if (dd < 5) {
      const int o = 127 + (l >> 4) * 8 - (l & 15) + (dd - 2) * 32;
      bf16x8 a1, a2;
#pragma unroll
      for (int j = 0; j < 8; ++j) {
        int p = o + j;
        int i1 = p - 64;
        a1[j] = ((unsigned)i1 < 128u) ? (bf16)hs[i1] : (bf16)0.f;
        int i2 = 191 - p;
        a2[j] = ((unsigned)i2 < 128u) ? (bf16)(-hs[i2]) : (bf16)0.f;
      }
      *reinterpret_cast<bf16x8*>(ws + WS_A1 + l * 64 + dd * 8) = a1;
      *reinterpret_cast<bf16x8*>(ws + WS_A2 + l * 64 + dd * 8) = a2;
    }
  }
}

// window load: 8 consecutive fp32 of one row -> bf16x8 fragment
template <bool SAFE>
__device__ __forceinline__ bf16x8 load_win(const float* __restrict__ yrow,
                                           int c) {
  bf16x8 b;
  if (SAFE || (c >= 0 && c <= 4096 - 8)) {
    float4 v0 = *reinterpret_cast<const float4*>(yrow + c);
    float4 v1 = *reinterpret_cast<const float4*>(yrow + c + 4);
    b[0] = (bf16)v0.x; b[1] = (bf16)v0.y; b[2] = (bf16)v0.z; b[3] = (bf16)v0.w;
    b[4] = (bf16)v1.x; b[5] = (bf16)v1.y; b[6] = (bf16)v1.z; b[7] = (bf16)v1.w;
  } else {
#pragma unroll
    for (int j = 0; j < 8; ++j) {
      int cc = c + j;
      b[j] = ((unsigned)cc < 4096u) ? (bf16)yrow[cc] : (bf16)0.f;
    }
  }
  return b;
}

template <bool SAFE>
__device__ __forceinline__ void interior_path(
    const float* __restrict__ y, const bf16* __restrict__ ws, float s,
    float* __restrict__ out, int chunk0, int b0, int lane) {
  const int li = lane & 15;
  const int quad = lane >> 4;
  const int wave = (threadIdx.x) >> 6;

  bf16x8 AG[9];
#pragma unroll
  for (int dd = 0; dd < 9; ++dd)
    AG[dd] = *reinterpret_cast<const bf16x8*>(ws + WS_AG + lane * 128 + dd * 8);

  const float* yrow = y + (size_t)(b0 + li) * 4096;
  const int iw = 16 * wave;
  // lane's first elem col for window dd at tile k: cb + 64k + (dd-4)*32
  const int cb = chunk0 + iw + quad * 8;

  bf16x8 B[9];
#pragma unroll
  for (int dd = 0; dd < 9; ++dd)
    B[dd] = load_win<SAFE>(yrow, cb + (dd - 4) * 32);

  float* orow = out + (size_t)(b0 + li) * 4096 + chunk0 + iw + quad * 4;
#pragma unroll
  for (int k = 0; k < 8; ++k) {
    bf16x8 n0, n1;
    if (k < 7) {   // prefetch next 2 windows; MFMAs below hide the latency
      n0 = load_win<SAFE>(yrow, cb + 64 * (k + 1) + 96);
      n1 = load_win<SAFE>(yrow, cb + 64 * (k + 1) + 128);
    }
    f32x4 acc0 = {0.f, 0.f, 0.f, 0.f};
    f32x4 acc1 = {0.f, 0.f, 0.f, 0.f};
    acc0 = __builtin_amdgcn_mfma_f32_16x16x32_bf16(AG[0], B[0], acc0, 0, 0, 0);
    acc1 = __builtin_amdgcn_mfma_f32_16x16x32_bf16(AG[1], B[1], acc1, 0, 0, 0);
    acc0 = __builtin_amdgcn_mfma_f32_16x16x32_bf16(AG[2], B[2], acc0, 0, 0, 0);
    acc1 = __builtin_amdgcn_mfma_f32_16x16x32_bf16(AG[3], B[3], acc1, 0, 0, 0);
    acc0 = __builtin_amdgcn_mfma_f32_16x16x32_bf16(AG[4], B[4], acc0, 0, 0, 0);
    acc1 = __builtin_amdgcn_mfma_f32_16x16x32_bf16(AG[5], B[5], acc1, 0, 0, 0);
    acc0 = __builtin_amdgcn_mfma_f32_16x16x32_bf16(AG[6], B[6], acc0, 0, 0, 0);
    acc1 = __builtin_amdgcn_mfma_f32_16x16x32_bf16(AG[7], B[7], acc1, 0, 0, 0);
    acc0 = __builtin_amdgcn_mfma_f32_16x16x32_bf16(AG[8], B[8], acc0, 0, 0, 0);
    bool do_store = true;
    if (!SAFE) {
      const int gc0 = chunk0 + iw + 64 * k;
      do_store = (gc0 >= 64 && gc0 < 4032);   // edge strips owned by edge blocks
    }
    if (do_store) {
      float4 xv;
#pragma unroll
      for (int e = 0; e < 4; ++e) {
        float su = s * (acc0[e] + acc1[e]);
        float ax = fabsf(su) - LAM;
        ax = ax > 0.f ? ax : 0.f;
        (&xv.x)[e] = 5.f * copysignf(ax, su);
      }
      *reinterpret_cast<float4*>(orow + 64 * k) = xv;
    }
    if (k < 7) {
#pragma unroll
      for (int r = 0; r < 7; ++r) B[r] = B[r + 2];
      B[7] = n0;
      B[8] = n1;
    }
  }
}

// ---------------- fused main: interior streaming + edge two-pass ----------
__global__ __launch_bounds__(256, 4) void ista_fused(
    const float* __restrict__ y, const bf16* __restrict__ ws,
    const float* __restrict__ step, float* __restrict__ out) {
  __shared__ __align__(16) bf16 buf[16 * PYE + 16 * PRE];  // edge path only
  const int tid = threadIdx.x;
  const int lane = tid & 63;
  const int li = lane & 15;
  const int quad = lane >> 4;
  const int wave = tid >> 6;
  const int bid = blockIdx.x;
  const float s = step[0];

  if (bid < 2048) {
    // chunk = bid>>8 -> all chunks of a row-group share an XCD (bid%8 const).
    const int chunk0 = (bid >> 8) * LC;
    const int b0 = (bid & 255) * 16;
    if (chunk0 != 0 && chunk0 != 3584) {
      interior_path<true>(y, ws, s, out, chunk0, b0, lane);
    } else {
      interior_path<false>(y, ws, s, out, chunk0, b0, lane);
    }
  } else {
    // ---------------- edge: exact two-pass on 64-col strips ----------------
    const int eid = bid - 2048;
    const int chunk0 = (eid & 1) ? (4096 - 64) : 0;
    const int b0 = (eid >> 1) * 16;
    bf16* ys = buf;                 // 16 x PYE, positions [-128, 224)
    bf16* rs = buf + 16 * PYE;      // 16 x PRE, -r at positions [-64, 144)

    bf16x8 A1[5], A2[5];
#pragma unroll
    for (int dd = 0; dd < 5; ++dd) {
      A1[dd] = *reinterpret_cast<const bf16x8*>(ws + WS_A1 + lane * 64 + dd * 8);
      A2[dd] = *reinterpret_cast<const bf16x8*>(ws + WS_A2 + lane * 64 + dd * 8);
    }

    {  // stage y: 352 elems = 88 float4 per row (guarded)
      const int rr = tid >> 4;
      const int t = tid & 15;
      const float* yrow = y + (size_t)(b0 + rr) * 4096;
      bf16* dst = ys + rr * PYE;
#pragma unroll
      for (int k = 0; k < 6; ++k) {
        int s4 = t + 16 * k;
        if (s4 < 88) {
          int l = chunk0 - 128 + s4 * 4;
          float4 v;
          if (l >= 0 && l <= 4096 - 4) {
            v = *reinterpret_cast<const float4*>(yrow + l);
          } else {
            v.x = ((unsigned)(l + 0) < 4096u) ? yrow[l + 0] : 0.f;
            v.y = ((unsigned)(l + 1) < 4096u) ? yrow[l + 1] : 0.f;
            v.z = ((unsigned)(l + 2) < 4096u) ? yrow[l + 2] : 0.f;
            v.w = ((unsigned)(l + 3) < 4096u) ? yrow[l + 3] : 0.f;
          }
          bf16x4 bv;
          bv[0] = (bf16)v.x; bv[1] = (bf16)v.y; bv[2] = (bf16)v.z; bv[3] = (bf16)v.w;
          *reinterpret_cast<bf16x4*>(dst + s4 * 4) = bv;
        }
      }
    }
    __syncthreads();

    // conv1: tiles i0 = -64+16t, t in [0,13); emit -r (truncated to [0,L))
    for (int t = wave; t < 13; t += 4) {
      const int i0 = -64 + 16 * t;
      f32x4 acc;
      {
        bf16x4 yv = *reinterpret_cast<const bf16x4*>(
            ys + li * PYE + (i0 + 128) + quad * 4);
        acc[0] = -(float)yv[0]; acc[1] = -(float)yv[1];
        acc[2] = -(float)yv[2]; acc[3] = -(float)yv[3];
      }
#pragma unroll
      for (int dd = 0; dd < 5; ++dd) {
        bf16x8 b = *reinterpret_cast<const bf16x8*>(
            ys + li * PYE + (i0 + (dd - 2) * 32 + 128) + quad * 8);
        acc = __builtin_amdgcn_mfma_f32_16x16x32_bf16(A1[dd], b, acc, 0, 0, 0);
      }
      bf16x4 rv;
#pragma unroll
      for (int e = 0; e < 4; ++e) {
        int g = chunk0 + i0 + quad * 4 + e;
        float v = ((unsigned)g < 4096u) ? acc[e] : 0.f;
        rv[e] = (bf16)v;
      }
      *reinterpret_cast<bf16x4*>(rs + li * PRE + (i0 + 64) + quad * 4) = rv;
    }
    __syncthreads();

    // conv2 + closed-form epilogue: 4 tiles, one per wave
    {
      const int i0 = 16 * wave;
      f32x4 acc = {0.f, 0.f, 0.f, 0.f};
#pragma unroll
      for (int dd = 0; dd < 5; ++dd) {
        bf16x8 b = *reinterpret_cast<const bf16x8*>(
            rs + li * PRE + (i0 + (dd - 2) * 32 + 64) + quad * 8);
        acc = __builtin_amdgcn_mfma_f32_16x16x32_bf16(A2[dd], b, acc, 0, 0, 0);
      }
      float4 xv;
#pragma unroll
      for (int e = 0; e < 4; ++e) {
        float su = s * acc[e];
        float ax = fabsf(su) - LAM;
        ax = ax > 0.f ? ax : 0.f;
        (&xv.x)[e] = 5.f * copysignf(ax, su);
      }
      *reinterpret_cast<float4*>(
          out + (size_t)(b0 + li) * 4096 + chunk0 + i0 + quad * 4) = xv;
    }
  }
}

extern "C" void kernel_launch(void* const* d_in, const int* in_sizes, int n_in,
                              void* d_out, int out_size, void* d_ws,
                              size_t ws_size, hipStream_t stream) {
  const float* y = (const float*)d_in[0];
  const float* h = (const float*)d_in[1];
  const float* s = (const float*)d_in[2];
  float* out = (float*)d_out;
  bf16* ws = (bf16*)d_ws;   // 32 KB used
  ista_prep<<<dim3(1), dim3(256), 0, stream>>>(h, ws);
  // 2048 interior blocks (cols [64,4032)) + 512 edge blocks (cols [0,64) and
  // [4032,4096)) — disjoint output columns, single launch after prep.
  ista_fused<<<dim3(2048 + 512), dim3(256), 0, stream>>>(y, ws, s, out);
}

// Round 5
// 135.799 us; speedup vs baseline: 1.2302x; 1.2302x over previous
//
#include <hip/hip_runtime.h>

// ISTA T=5, LAM=0.1, B=L=4096, K=128.
// R8: R5 structure (stage->barrier->compute) with branch-free global_load_lds
//  DMA staging (R7 fixed: DMA is ALWAYS full-wave; OOB halo chunks source a
//  zero block in ws instead of masking lanes -> lane0 always active -> the
//  wave-uniform-base + lane*16 LDS contract is always met).
//  u = corr(y - corr(y,h), rev(h)) == (interior) one 255-tap correlation
//    G[t] = [t in [-63,64]] h[64-t] - ac[|t-1|],  ac[tau]=sum_m h[m]h[m+tau].
//  Interior: DMA y (fp32) -> LDS, cvt to bf16 at fragment-load time inside the
//  compute loop (sliding 9-window registers, 2 new windows/tile).
//  r-truncation affects cols [0,64) u [L-64,L): exact two-pass edge blocks
//  (same launch, disjoint columns) fix those strips.
//  ISTA closed form (constant u): x_5 = 5*soft(s*u, LAM).

typedef __bf16 bf16;
typedef __bf16 bf16x4 __attribute__((ext_vector_type(4)));
typedef __bf16 bf16x8 __attribute__((ext_vector_type(8)));
typedef float f32x4 __attribute__((ext_vector_type(4)));

#define LC 512       // L-chunk per interior block
#define PITCH 804    // fp32 LDS row pitch (dwords); 804%32=4 -> spread banks
#define CPR 201      // 16B chunks per row (804*4/16)
#define NCHK 3216    // 16 rows * 201 chunks (valid data)
#define NGRP 52      // staged 64-chunk groups (52*64=3328 incl. pad tail)
#define LDSB (3328 * 16)   // 53248 B
#define LAM 0.1f
// ws layout in bf16 elems (16-B aligned fragments):
#define WS_AG 0        // AG frag:  lane*128 + dd*8, dd<9  (per-lane gap 72..128)
#define WS_ZERO 80     // 8 bf16 zeros inside lane0's AG gap (byte 160, 16B-al)
#define WS_A1 8192     // A1e frag: lane*64  + dd*8, dd<5
#define WS_A2 12288    // A2e frag: lane*64  + dd*8, dd<5
// edge-path LDS partition:
#define PYE 360        // y strip pitch (352 needed)
#define PRE 216        // r strip pitch (208 needed)

// ---------------- prep: G + lane-layout A-fragment tables ----------------
__global__ __launch_bounds__(256) void ista_prep(const float* __restrict__ h,
                                                 bf16* __restrict__ ws) {
  __shared__ float hs[256];    // h zero-padded
  __shared__ float acp[256];   // autocorr partials
  __shared__ bf16 gp[384];     // G[t] at p=t+144, zero outside
  const int tid = threadIdx.x;
  hs[tid] = (tid < 128) ? h[tid] : 0.f;
  gp[tid] = (bf16)0.f;
  if (tid < 128) gp[256 + tid] = (bf16)0.f;
  __syncthreads();
  const int tau = tid & 127;
  {  // split ac over two halves x 4 accumulators (short dep chains)
    const int m0 = (tid >> 7) * 64;
    float p0 = 0.f, p1 = 0.f, p2 = 0.f, p3 = 0.f;
    for (int m = m0; m < m0 + 64; m += 4) {
      p0 += hs[m] * hs[m + tau];     p1 += hs[m + 1] * hs[m + 1 + tau];
      p2 += hs[m + 2] * hs[m + 2 + tau]; p3 += hs[m + 3] * hs[m + 3 + tau];
    }
    acp[tid] = (p0 + p1) + (p2 + p3);
  }
  __syncthreads();
  if (tid < 128) {
    float ac = acp[tid] + acp[tid + 128];
    float g1 = (tau <= 63) ? hs[63 - tau] : 0.f;
    gp[145 + tau] = (bf16)(g1 - ac);
    if (tau > 0) {
      float g2 = (tau <= 64) ? hs[63 + tau] : 0.f;
      gp[145 - tau] = (bf16)(g2 - ac);
    }
  }
  __syncthreads();
  // AG lane-layout: A[m=li][k=quad*8+j] = G[144 + quad*8 - li + (dd-4)*32 + j]
  for (int i = tid; i < 1024; i += 256) {
    const int l = i >> 4, dd = i & 15;
    if (dd < 9) {
      const int o = 144 + (l >> 4) * 8 - (l & 15) + (dd - 4) * 32;
      bf16x8 a;
#pragma unroll
      for (int j = 0; j < 8; ++j) a[j] = gp[o + j];
      *reinterpret_cast<bf16x8*>(ws + WS_AG + l * 128 + dd * 8) = a;
    }
  }
  if (tid < 8) ws[WS_ZERO + tid] = (bf16)0.f;   // 16-B zero block for DMA halo
  // edge Toeplitz tables: h1p[p]=h[p-64], h2p[p]=-h[191-p] (zero outside)
  for (int i = tid; i < 512; i += 256) {
    const int l = i >> 3, dd = i & 7;
    if (dd < 5) {
      const int o = 127 + (l >> 4) * 8 - (l & 15) + (dd - 2) * 32;
      bf16x8 a1, a2;
#pragma unroll
      for (int j = 0; j < 8; ++j) {
        int p = o + j;
        int i1 = p - 64;
        a1[j] = ((unsigned)i1 < 128u) ? (bf16)hs[i1] : (bf16)0.f;
        int i2 = 191 - p;
        a2[j] = ((unsigned)i2 < 128u) ? (bf16)(-hs[i2]) : (bf16)0.f;
      }
      *reinterpret_cast<bf16x8*>(ws + WS_A1 + l * 64 + dd * 8) = a1;
      *reinterpret_cast<bf16x8*>(ws + WS_A2 + l * 64 + dd * 8) = a2;
    }
  }
}

__device__ __forceinline__ void async_copy16(const float* src, void* lds_dst) {
  __builtin_amdgcn_global_load_lds(
      (const __attribute__((address_space(1))) void*)src,
      (__attribute__((address_space(3))) void*)lds_dst, 16, 0, 0);
}

// fp32 LDS row -> bf16x8 fragment (8 consecutive elems starting at dword c)
__device__ __forceinline__ bf16x8 load_frag(const float* __restrict__ yl,
                                            int c) {
  float4 v0 = *reinterpret_cast<const float4*>(yl + c);
  float4 v1 = *reinterpret_cast<const float4*>(yl + c + 4);
  bf16x8 b;
  b[0] = (bf16)v0.x; b[1] = (bf16)v0.y; b[2] = (bf16)v0.z; b[3] = (bf16)v0.w;
  b[4] = (bf16)v1.x; b[5] = (bf16)v1.y; b[6] = (bf16)v1.z; b[7] = (bf16)v1.w;
  return b;
}

// ---------------- fused main: interior DMA-staged + edge two-pass ---------
__global__ __launch_bounds__(256) void ista_fused(
    const float* __restrict__ y, const bf16* __restrict__ ws,
    const float* __restrict__ step, float* __restrict__ out) {
  __shared__ __align__(16) char smem[LDSB];   // 53248 B
  const int tid = threadIdx.x;
  const int lane = tid & 63;
  const int li = lane & 15;
  const int quad = lane >> 4;
  const int wave = tid >> 6;
  const int bid = blockIdx.x;
  const float s = step[0];

  if (bid < 2048) {
    // chunk = bid>>8 -> all chunks of a row-group share an XCD (bid%8 const).
    const int chunk0 = (bid >> 8) * LC;
    const int b0 = (bid & 255) * 16;

    // A-fragments from ws (independent global loads; drain with the DMA)
    bf16x8 AG[9];
#pragma unroll
    for (int dd = 0; dd < 9; ++dd)
      AG[dd] = *reinterpret_cast<const bf16x8*>(ws + WS_AG + lane * 128 + dd * 8);

    // ---- DMA stage: y fp32 -> LDS, linear [16][PITCH] layout ----
    // chunk q (16B) = row r=q/CPR, dword col 4*cq; global col g=chunk0-128+4cq.
    // ALWAYS full-wave: OOB halo / pad chunks DMA from the 16-B zero block in
    // ws (never mask lanes -> lane0 base contract of global_load_lds holds).
    {
      const float* zsrc = reinterpret_cast<const float*>(ws + WS_ZERO);
#pragma unroll
      for (int kk = 0; kk < 13; ++kk) {
        const int q = (wave + 4 * kk) * 64 + lane;   // < 3328
        const int r = q / CPR;
        const int cq = q - r * CPR;
        int g = chunk0 - 128 + cq * 4;
        if (cq >= 200) g = -1;                       // pad chunk -> zeros
        const float* src = (r < 16 && (unsigned)g <= 4092u)
                               ? (y + (size_t)(b0 + r) * 4096 + g)
                               : zsrc;
        async_copy16(src, smem + q * 16);
      }
    }
    __syncthreads();   // drains vmcnt (DMA) + lgkmcnt

    // ---- compute: 8 tiles/wave, sliding 9-window regs, cvt at load ----
    const float* yl = reinterpret_cast<const float*>(smem) + li * PITCH;
    const int iw = 16 * wave;
    const int cb = 128 + iw + quad * 8;     // LDS dword col of window dd=4
    bf16x8 B[9];
#pragma unroll
    for (int dd = 0; dd < 9; ++dd)
      B[dd] = load_frag(yl, cb + (dd - 4) * 32);

    float* orow = out + (size_t)(b0 + li) * 4096 + chunk0 + iw + quad * 4;
#pragma unroll
    for (int k = 0; k < 8; ++k) {
      bf16x8 n0, n1;
      if (k < 7) {   // next 2 windows; LDS latency hides under MFMAs
        n0 = load_frag(yl, cb + 64 * (k + 1) + 96);
        n1 = load_frag(yl, cb + 64 * (k + 1) + 128);
      }
      f32x4 acc0 = {0.f, 0.f, 0.f, 0.f};
      f32x4 acc1 = {0.f, 0.f, 0.f, 0.f};
      acc0 = __builtin_amdgcn_mfma_f32_16x16x32_bf16(AG[0], B[0], acc0, 0, 0, 0);
      acc1 = __builtin_amdgcn_mfma_f32_16x16x32_bf16(AG[1], B[1], acc1, 0, 0, 0);
      acc0 = __builtin_amdgcn_mfma_f32_16x16x32_bf16(AG[2], B[2], acc0, 0, 0, 0);
      acc1 = __builtin_amdgcn_mfma_f32_16x16x32_bf16(AG[3], B[3], acc1, 0, 0, 0);
      acc0 = __builtin_amdgcn_mfma_f32_16x16x32_bf16(AG[4], B[4], acc0, 0, 0, 0);
      acc1 = __builtin_amdgcn_mfma_f32_16x16x32_bf16(AG[5], B[5], acc1, 0, 0, 0);
      acc0 = __builtin_amdgcn_mfma_f32_16x16x32_bf16(AG[6], B[6], acc0, 0, 0, 0);
      acc1 = __builtin_amdgcn_mfma_f32_16x16x32_bf16(AG[7], B[7], acc1, 0, 0, 0);
      acc0 = __builtin_amdgcn_mfma_f32_16x16x32_bf16(AG[8], B[8], acc0, 0, 0, 0);
      const int gc0 = chunk0 + iw + 64 * k;
      if (gc0 >= 64 && gc0 < 4032) {   // edge strips owned by edge blocks
        float4 xv;
#pragma unroll
        for (int e = 0; e < 4; ++e) {
          float su = s * (acc0[e] + acc1[e]);
          float ax = fabsf(su) - LAM;
          ax = ax > 0.f ? ax : 0.f;
          (&xv.x)[e] = 5.f * copysignf(ax, su);
        }
        *reinterpret_cast<float4*>(orow + 64 * k) = xv;
      }
      if (k < 7) {
#pragma unroll
        for (int r = 0; r < 7; ++r) B[r] = B[r + 2];
        B[7] = n0;
        B[8] = n1;
      }
    }
  } else {
    // ---------------- edge: exact two-pass on 64-col strips ----------------
    const int eid = bid - 2048;
    const int chunk0 = (eid & 1) ? (4096 - 64) : 0;
    const int b0 = (eid >> 1) * 16;
    bf16* ys = reinterpret_cast<bf16*>(smem);      // 16 x PYE, [-128, 224)
    bf16* rs = ys + 16 * PYE;                      // 16 x PRE, -r at [-64, 144)

    bf16x8 A1[5], A2[5];
#pragma unroll
    for (int dd = 0; dd < 5; ++dd) {
      A1[dd] = *reinterpret_cast<const bf16x8*>(ws + WS_A1 + lane * 64 + dd * 8);
      A2[dd] = *reinterpret_cast<const bf16x8*>(ws + WS_A2 + lane * 64 + dd * 8);
    }

    {  // stage y: 352 elems = 88 float4 per row (guarded)
      const int rr = tid >> 4;
      const int t = tid & 15;
      const float* yrow = y + (size_t)(b0 + rr) * 4096;
      bf16* dst = ys + rr * PYE;
#pragma unroll
      for (int k = 0; k < 6; ++k) {
        int s4 = t + 16 * k;
        if (s4 < 88) {
          int l = chunk0 - 128 + s4 * 4;
          float4 v;
          if (l >= 0 && l <= 4096 - 4) {
            v = *reinterpret_cast<const float4*>(yrow + l);
          } else {
            v.x = ((unsigned)(l + 0) < 4096u) ? yrow[l + 0] : 0.f;
            v.y = ((unsigned)(l + 1) < 4096u) ? yrow[l + 1] : 0.f;
            v.z = ((unsigned)(l + 2) < 4096u) ? yrow[l + 2] : 0.f;
            v.w = ((unsigned)(l + 3) < 4096u) ? yrow[l + 3] : 0.f;
          }
          bf16x4 bv;
          bv[0] = (bf16)v.x; bv[1] = (bf16)v.y; bv[2] = (bf16)v.z; bv[3] = (bf16)v.w;
          *reinterpret_cast<bf16x4*>(dst + s4 * 4) = bv;
        }
      }
    }
    __syncthreads();

    // conv1: tiles i0 = -64+16t, t in [0,13); emit -r (truncated to [0,L))
    for (int t = wave; t < 13; t += 4) {
      const int i0 = -64 + 16 * t;
      f32x4 acc;
      {
        bf16x4 yv = *reinterpret_cast<const bf16x4*>(
            ys + li * PYE + (i0 + 128) + quad * 4);
        acc[0] = -(float)yv[0]; acc[1] = -(float)yv[1];
        acc[2] = -(float)yv[2]; acc[3] = -(float)yv[3];
      }
#pragma unroll
      for (int dd = 0; dd < 5; ++dd) {
        bf16x8 b = *reinterpret_cast<const bf16x8*>(
            ys + li * PYE + (i0 + (dd - 2) * 32 + 128) + quad * 8);
        acc = __builtin_amdgcn_mfma_f32_16x16x32_bf16(A1[dd], b, acc, 0, 0, 0);
      }
      bf16x4 rv;
#pragma unroll
      for (int e = 0; e < 4; ++e) {
        int g = chunk0 + i0 + quad * 4 + e;
        float v = ((unsigned)g < 4096u) ? acc[e] : 0.f;
        rv[e] = (bf16)v;
      }
      *reinterpret_cast<bf16x4*>(rs + li * PRE + (i0 + 64) + quad * 4) = rv;
    }
    __syncthreads();

    // conv2 + closed-form epilogue: 4 tiles, one per wave
    {
      const int i0 = 16 * wave;
      f32x4 acc = {0.f, 0.f, 0.f, 0.f};
#pragma unroll
      for (int dd = 0; dd < 5; ++dd) {
        bf16x8 b = *reinterpret_cast<const bf16x8*>(
            rs + li * PRE + (i0 + (dd - 2) * 32 + 64) + quad * 8);
        acc = __builtin_amdgcn_mfma_f32_16x16x32_bf16(A2[dd], b, acc, 0, 0, 0);
      }
      float4 xv;
#pragma unroll
      for (int e = 0; e < 4; ++e) {
        float su = s * acc[e];
        float ax = fabsf(su) - LAM;
        ax = ax > 0.f ? ax : 0.f;
        (&xv.x)[e] = 5.f * copysignf(ax, su);
      }
      *reinterpret_cast<float4*>(
          out + (size_t)(b0 + li) * 4096 + chunk0 + i0 + quad * 4) = xv;
    }
  }
}

extern "C" void kernel_launch(void* const* d_in, const int* in_sizes, int n_in,
                              void* d_out, int out_size, void* d_ws,
                              size_t ws_size, hipStream_t stream) {
  const float* y = (const float*)d_in[0];
  const float* h = (const float*)d_in[1];
  const float* s = (const float*)d_in[2];
  float* out = (float*)d_out;
  bf16* ws = (bf16*)d_ws;   // 32 KB used
  ista_prep<<<dim3(1), dim3(256), 0, stream>>>(h, ws);
  // 2048 interior blocks (cols [64,4032)) + 512 edge blocks (cols [0,64) and
  // [4032,4096)) — disjoint output columns, single launch after prep.
  ista_fused<<<dim3(2048 + 512), dim3(256), 0, stream>>>(y, ws, s, out);
}

// Round 6
// 133.462 us; speedup vs baseline: 1.2518x; 1.0175x over previous
//
#include <hip/hip_runtime.h>

// ISTA T=5, LAM=0.1, B=L=4096, K=128.
// R9: persistent stream blocks + 4-slot LDS ring DMA pipeline.
//  u = corr(y - corr(y,h), rev(h)) == (interior) one 255-tap correlation
//    G[t] = [t in [-63,64]] h[64-t] - ac[|t-1|],  ac[tau]=sum_m h[m]h[m+tau].
//  512 stream blocks (2/CU), each owns a 16-row x 2048-col strip = 8 steps of
//  256 cols. LDS ring: 4 segments x 256 dw per row (pitch 1028 dw). Per step:
//    __syncthreads(); DMA seg k+3 (global_load_lds, full compute-step to
//    land); compute step k from segs k..k+2.
//  Writer slot (k+3)&3 disjoint from reader slots {k,k+1,k+2}&3; prior
//  readers of the reused slot finished before the barrier -> race-free.
//  r-truncation affects cols [0,64) u [L-64,L): exact two-pass edge blocks
//  (same launch, disjoint columns) fix those strips.
//  ISTA closed form (constant u): x_5 = 5*soft(s*u, LAM).

typedef __bf16 bf16;
typedef __bf16 bf16x4 __attribute__((ext_vector_type(4)));
typedef __bf16 bf16x8 __attribute__((ext_vector_type(8)));
typedef float f32x4 __attribute__((ext_vector_type(4)));

#define LAM 0.1f
#define RPITCH 1028              // fp32 dwords per LDS row (4 segs x 256 + 4)
#define LDSB (16 * RPITCH * 4)   // 65792 B (2 blocks/CU)
// ws layout in bf16 elems (16-B aligned fragments):
#define WS_AG 0        // AG frag:  lane*128 + dd*8, dd<9 (gap 72..128 per lane)
#define WS_ZERO 80     // 8 bf16 zeros inside lane0's AG gap (16-B aligned)
#define WS_A1 8192     // A1e frag: lane*64  + dd*8, dd<5
#define WS_A2 12288    // A2e frag: lane*64  + dd*8, dd<5
// edge-path LDS partition:
#define PYE 360        // y strip pitch (352 needed)
#define PRE 216        // r strip pitch (208 needed)

// ---------------- prep: G + lane-layout A-fragment tables ----------------
__global__ __launch_bounds__(256) void ista_prep(const float* __restrict__ h,
                                                 bf16* __restrict__ ws) {
  __shared__ float hs[256];    // h zero-padded
  __shared__ float acp[256];   // autocorr partials
  __shared__ bf16 gp[384];     // G[t] at p=t+144, zero outside
  const int tid = threadIdx.x;
  hs[tid] = (tid < 128) ? h[tid] : 0.f;
  gp[tid] = (bf16)0.f;
  if (tid < 128) gp[256 + tid] = (bf16)0.f;
  __syncthreads();
  const int tau = tid & 127;
  {  // split ac over two halves x 4 accumulators (short dep chains)
    const int m0 = (tid >> 7) * 64;
    float p0 = 0.f, p1 = 0.f, p2 = 0.f, p3 = 0.f;
    for (int m = m0; m < m0 + 64; m += 4) {
      p0 += hs[m] * hs[m + tau];     p1 += hs[m + 1] * hs[m + 1 + tau];
      p2 += hs[m + 2] * hs[m + 2 + tau]; p3 += hs[m + 3] * hs[m + 3 + tau];
    }
    acp[tid] = (p0 + p1) + (p2 + p3);
  }
  __syncthreads();
  if (tid < 128) {
    float ac = acp[tid] + acp[tid + 128];
    float g1 = (tau <= 63) ? hs[63 - tau] : 0.f;
    gp[145 + tau] = (bf16)(g1 - ac);
    if (tau > 0) {
      float g2 = (tau <= 64) ? hs[63 + tau] : 0.f;
      gp[145 - tau] = (bf16)(g2 - ac);
    }
  }
  __syncthreads();
  // AG lane-layout: A[m=li][k=quad*8+j] = G[144 + quad*8 - li + (dd-4)*32 + j]
  for (int i = tid; i < 1024; i += 256) {
    const int l = i >> 4, dd = i & 15;
    if (dd < 9) {
      const int o = 144 + (l >> 4) * 8 - (l & 15) + (dd - 4) * 32;
      bf16x8 a;
#pragma unroll
      for (int j = 0; j < 8; ++j) a[j] = gp[o + j];
      *reinterpret_cast<bf16x8*>(ws + WS_AG + l * 128 + dd * 8) = a;
    }
  }
  if (tid < 8) ws[WS_ZERO + tid] = (bf16)0.f;   // 16-B zero block for DMA halo
  // edge Toeplitz tables: h1p[p]=h[p-64], h2p[p]=-h[191-p] (zero outside)
  for (int i = tid; i < 512; i += 256) {
    const int l = i >> 3, dd = i & 7;
    if (dd < 5) {
      const int o = 127 + (l >> 4) * 8 - (l & 15) + (dd - 2) * 32;
      bf16x8 a1, a2;
#pragma unroll
      for (int j = 0; j < 8; ++j) {
        int p = o + j;
        int i1 = p - 64;
        a1[j] = ((unsigned)i1 < 128u) ? (bf16)hs[i1] : (bf16)0.f;
        int i2 = 191 - p;
        a2[j] = ((unsigned)i2 < 128u) ? (bf16)(-hs[i2]) : (bf16)0.f;
      }
      *reinterpret_cast<bf16x8*>(ws + WS_A1 + l * 64 + dd * 8) = a1;
      *reinterpret_cast<bf16x8*>(ws + WS_A2 + l * 64 + dd * 8) = a2;
    }
  }
}

__device__ __forceinline__ void async_copy16(const float* src, void* lds_dst) {
  __builtin_amdgcn_global_load_lds(
      (const __attribute__((address_space(1))) void*)src,
      (__attribute__((address_space(3))) void*)lds_dst, 16, 0, 0);
}

// fp32 LDS row -> bf16x8 fragment (8 consecutive dwords starting at c)
__device__ __forceinline__ bf16x8 load_frag(const float* __restrict__ yl,
                                            int c) {
  float4 v0 = *reinterpret_cast<const float4*>(yl + c);
  float4 v1 = *reinterpret_cast<const float4*>(yl + c + 4);
  bf16x8 b;
  b[0] = (bf16)v0.x; b[1] = (bf16)v0.y; b[2] = (bf16)v0.z; b[3] = (bf16)v0.w;
  b[4] = (bf16)v1.x; b[5] = (bf16)v1.y; b[6] = (bf16)v1.z; b[7] = (bf16)v1.w;
  return b;
}

// ---------------- fused: stream-ring interior + edge two-pass -------------
__global__ __launch_bounds__(256) void ista_fused(
    const float* __restrict__ y, const bf16* __restrict__ ws,
    const float* __restrict__ step, float* __restrict__ out) {
  __shared__ __align__(16) char smem[LDSB];
  const int tid = threadIdx.x;
  const int lane = tid & 63;
  const int li = lane & 15;
  const int quad = lane >> 4;
  const int wave = tid >> 6;
  const int bid = blockIdx.x;
  const float s = step[0];

  if (bid < 512) {
    // ---------------- stream: 16 rows x 2048 cols, 8 steps of 256 ----------
    const int b0 = (bid >> 1) * 16;
    const int cblk = (bid & 1) * 2048;

    bf16x8 AG[9];
#pragma unroll
    for (int dd = 0; dd < 9; ++dd)
      AG[dd] = *reinterpret_cast<const bf16x8*>(ws + WS_AG + lane * 128 + dd * 8);

    const float* zsrc = reinterpret_cast<const float*>(ws + WS_ZERO);
    // seg m covers abs cols [cblk+256(m-1), cblk+256m); slot m&3; 16 wave-
    // issues per seg (one per row), 4 per wave. OOB segs (uniform) DMA zeros.
    auto issue_seg = [&](int m) {
      const int base = cblk + 256 * (m - 1);
      const bool oob = (base < 0) | (base >= 4096);
      const int slotdw = (m & 3) * 256;
#pragma unroll
      for (int t = 0; t < 4; ++t) {
        const int r = (wave << 2) + t;
        const float* src =
            oob ? zsrc : (y + (size_t)(b0 + r) * 4096 + base + (lane << 2));
        char* dst = smem + ((r * RPITCH + slotdw) << 2) + (lane << 4);
        async_copy16(src, dst);
      }
    };
    issue_seg(0); issue_seg(1); issue_seg(2);   // prologue: segs for step 0

    const int qo = quad << 3;
    const float* rowp = reinterpret_cast<const float*>(smem) + li * RPITCH;
    float* orow = out + (size_t)(b0 + li) * 4096 + cblk + (quad << 2);

    for (int k = 0; k < 8; ++k) {
      __syncthreads();                 // segs <= k+2 landed; slot k+3 free
      if (k < 7) issue_seg(k + 3);     // overlaps the whole compute below
      const int rcw = (k << 8) + (wave << 4);   // this wave's first tile col
      // windows dd at tile rc: ring dword ((rc + (dd-4)*32 + qo + 256) & 1023)
      bf16x8 B[9];
#pragma unroll
      for (int dd = 0; dd < 9; ++dd)
        B[dd] = load_frag(rowp, (rcw + (dd - 4) * 32 + qo + 256) & 1023);
#pragma unroll
      for (int j = 0; j < 4; ++j) {    // tiles rc = rcw + 64j
        bf16x8 n0, n1;
        if (j < 3) {                   // prefetch next tile's 2 new windows
          n0 = load_frag(rowp, (rcw + 64 * (j + 1) + 96 + qo + 256) & 1023);
          n1 = load_frag(rowp, (rcw + 64 * (j + 1) + 128 + qo + 256) & 1023);
        }
        f32x4 acc0 = {0.f, 0.f, 0.f, 0.f};
        f32x4 acc1 = {0.f, 0.f, 0.f, 0.f};
        acc0 = __builtin_amdgcn_mfma_f32_16x16x32_bf16(AG[0], B[0], acc0, 0, 0, 0);
        acc1 = __builtin_amdgcn_mfma_f32_16x16x32_bf16(AG[1], B[1], acc1, 0, 0, 0);
        acc0 = __builtin_amdgcn_mfma_f32_16x16x32_bf16(AG[2], B[2], acc0, 0, 0, 0);
        acc1 = __builtin_amdgcn_mfma_f32_16x16x32_bf16(AG[3], B[3], acc1, 0, 0, 0);
        acc0 = __builtin_amdgcn_mfma_f32_16x16x32_bf16(AG[4], B[4], acc0, 0, 0, 0);
        acc1 = __builtin_amdgcn_mfma_f32_16x16x32_bf16(AG[5], B[5], acc1, 0, 0, 0);
        acc0 = __builtin_amdgcn_mfma_f32_16x16x32_bf16(AG[6], B[6], acc0, 0, 0, 0);
        acc1 = __builtin_amdgcn_mfma_f32_16x16x32_bf16(AG[7], B[7], acc1, 0, 0, 0);
        acc0 = __builtin_amdgcn_mfma_f32_16x16x32_bf16(AG[8], B[8], acc0, 0, 0, 0);
        const int tabs = cblk + rcw + (j << 6);
        if (tabs >= 64 && tabs < 4032) {   // edge strips owned by edge blocks
          float4 xv;
#pragma unroll
          for (int e = 0; e < 4; ++e) {
            float su = s * (acc0[e] + acc1[e]);
            float ax = fabsf(su) - LAM;
            ax = ax > 0.f ? ax : 0.f;
            (&xv.x)[e] = 5.f * copysignf(ax, su);
          }
          *reinterpret_cast<float4*>(orow + rcw + (j << 6)) = xv;
        }
        if (j < 3) {
          B[0] = B[2]; B[1] = B[3]; B[2] = B[4]; B[3] = B[5]; B[4] = B[6];
          B[5] = B[7]; B[6] = B[8]; B[7] = n0; B[8] = n1;
        }
      }
    }
  } else {
    // ---------------- edge: exact two-pass on 64-col strips ----------------
    const int eid = bid - 512;
    const int chunk0 = (eid & 1) ? (4096 - 64) : 0;
    const int b0 = (eid >> 1) * 16;
    bf16* ys = reinterpret_cast<bf16*>(smem);      // 16 x PYE, [-128, 224)
    bf16* rs = ys + 16 * PYE;                      // 16 x PRE, -r at [-64, 144)

    bf16x8 A1[5], A2[5];
#pragma unroll
    for (int dd = 0; dd < 5; ++dd) {
      A1[dd] = *reinterpret_cast<const bf16x8*>(ws + WS_A1 + lane * 64 + dd * 8);
      A2[dd] = *reinterpret_cast<const bf16x8*>(ws + WS_A2 + lane * 64 + dd * 8);
    }

    {  // stage y: 352 elems = 88 float4 per row (guarded)
      const int rr = tid >> 4;
      const int t = tid & 15;
      const float* yrow = y + (size_t)(b0 + rr) * 4096;
      bf16* dst = ys + rr * PYE;
#pragma unroll
      for (int k = 0; k < 6; ++k) {
        int s4 = t + 16 * k;
        if (s4 < 88) {
          int l = chunk0 - 128 + s4 * 4;
          float4 v;
          if (l >= 0 && l <= 4096 - 4) {
            v = *reinterpret_cast<const float4*>(yrow + l);
          } else {
            v.x = ((unsigned)(l + 0) < 4096u) ? yrow[l + 0] : 0.f;
            v.y = ((unsigned)(l + 1) < 4096u) ? yrow[l + 1] : 0.f;
            v.z = ((unsigned)(l + 2) < 4096u) ? yrow[l + 2] : 0.f;
            v.w = ((unsigned)(l + 3) < 4096u) ? yrow[l + 3] : 0.f;
          }
          bf16x4 bv;
          bv[0] = (bf16)v.x; bv[1] = (bf16)v.y; bv[2] = (bf16)v.z; bv[3] = (bf16)v.w;
          *reinterpret_cast<bf16x4*>(dst + s4 * 4) = bv;
        }
      }
    }
    __syncthreads();

    // conv1: tiles i0 = -64+16t, t in [0,13); emit -r (truncated to [0,L))
    for (int t = wave; t < 13; t += 4) {
      const int i0 = -64 + 16 * t;
      f32x4 acc;
      {
        bf16x4 yv = *reinterpret_cast<const bf16x4*>(
            ys + li * PYE + (i0 + 128) + quad * 4);
        acc[0] = -(float)yv[0]; acc[1] = -(float)yv[1];
        acc[2] = -(float)yv[2]; acc[3] = -(float)yv[3];
      }
#pragma unroll
      for (int dd = 0; dd < 5; ++dd) {
        bf16x8 b = *reinterpret_cast<const bf16x8*>(
            ys + li * PYE + (i0 + (dd - 2) * 32 + 128) + quad * 8);
        acc = __builtin_amdgcn_mfma_f32_16x16x32_bf16(A1[dd], b, acc, 0, 0, 0);
      }
      bf16x4 rv;
#pragma unroll
      for (int e = 0; e < 4; ++e) {
        int g = chunk0 + i0 + quad * 4 + e;
        float v = ((unsigned)g < 4096u) ? acc[e] : 0.f;
        rv[e] = (bf16)v;
      }
      *reinterpret_cast<bf16x4*>(rs + li * PRE + (i0 + 64) + quad * 4) = rv;
    }
    __syncthreads();

    // conv2 + closed-form epilogue: 4 tiles, one per wave
    {
      const int i0 = 16 * wave;
      f32x4 acc = {0.f, 0.f, 0.f, 0.f};
#pragma unroll
      for (int dd = 0; dd < 5; ++dd) {
        bf16x8 b = *reinterpret_cast<const bf16x8*>(
            rs + li * PRE + (i0 + (dd - 2) * 32 + 64) + quad * 8);
        acc = __builtin_amdgcn_mfma_f32_16x16x32_bf16(A2[dd], b, acc, 0, 0, 0);
      }
      float4 xv;
#pragma unroll
      for (int e = 0; e < 4; ++e) {
        float su = s * acc[e];
        float ax = fabsf(su) - LAM;
        ax = ax > 0.f ? ax : 0.f;
        (&xv.x)[e] = 5.f * copysignf(ax, su);
      }
      *reinterpret_cast<float4*>(
          out + (size_t)(b0 + li) * 4096 + chunk0 + i0 + quad * 4) = xv;
    }
  }
}

extern "C" void kernel_launch(void* const* d_in, const int* in_sizes, int n_in,
                              void* d_out, int out_size, void* d_ws,
                              size_t ws_size, hipStream_t stream) {
  const float* y = (const float*)d_in[0];
  const float* h = (const float*)d_in[1];
  const float* s = (const float*)d_in[2];
  float* out = (float*)d_out;
  bf16* ws = (bf16*)d_ws;   // 32 KB used
  ista_prep<<<dim3(1), dim3(256), 0, stream>>>(h, ws);
  // 512 stream blocks (cols [64,4032), pipelined) + 512 edge blocks (cols
  // [0,64) and [4032,4096)) — disjoint output columns, one launch after prep.
  ista_fused<<<dim3(512 + 512), dim3(256), 0, stream>>>(y, ws, s, out);
}